// Round 4
// baseline (1446.907 us; speedup 1.0000x reference)
//
#include <hip/hip_runtime.h>

// LSTMCellModel: only seq row 1023 feeds the output => batch-1 recurrence.
// 2 dispatches: k_init | k_fused (persistent, 256 WGs x 512 thr, 1 WG/CU).
//   WGs 0..127   = cell1 (pin whh1 rows in VGPRs, 64 f/thread; A1 on the fly; FC).
//   WGs 128..255 = cell2 (pin whh2 rows; A2 on the fly).
// FLAGLESS handoff: all h/c handoff buffers are per-t write-once arrays,
// pre-filled with a NaN sentinel; consumers poll the data words themselves
// (RELAXED agent loads) until != sentinel. h,c are always finite => safe.
// ws (floats): zbuf[1024] | htmpB[128*1024] | Hh[128*1024] | c1B[128*1024] | c2B[128*1024]

#define IN_DIM  512
#define HDIM    1024
#define NSTEP   128
#define ODIM    1000
#define NWGH    128
#define NTHR    512
#define SENT    0x7FC00001u
#define WIH_LD  528   // 528 % 32 == 16 -> gate-group windows at banks {0,16} (2-way, free)

__device__ __forceinline__ float sigf(float x) { return 1.f / (1.f + __expf(-x)); }

__global__ void k_init(float* __restrict__ zbuf, unsigned int* __restrict__ bufs) {
    int i = threadIdx.x + blockIdx.x * blockDim.x;   // 128 WGs x 512
    if (i < HDIM) zbuf[i] = 0.f;
    const int n4 = 4 * NSTEP * HDIM / 4;             // 4 buffers as uint4
    uint4 s = make_uint4(SENT, SENT, SENT, SENT);
    for (int j = i; j < n4; j += NWGH * NTHR) ((uint4*)bufs)[j] = s;
}

// poll a word until it is not the sentinel (RELAXED agent load = LLC-coherent)
__device__ __forceinline__ float poll_f(const float* p) {
    unsigned int u = __hip_atomic_load((const unsigned int*)p,
                                       __ATOMIC_RELAXED, __HIP_MEMORY_SCOPE_AGENT);
    while (u == SENT)
        u = __hip_atomic_load((const unsigned int*)p,
                              __ATOMIC_RELAXED, __HIP_MEMORY_SCOPE_AGENT);
    return __uint_as_float(u);
}

// poll + stage h (1024 f) into hs with the XOR swizzle:
// logical i=(c=i>>6, g=(i>>2)&15, e=i&3) stored at phys c*64+((g+c)&15)*4+e
__device__ __forceinline__ void load_h_poll(const float* __restrict__ hin,
                                            float* __restrict__ hs, int tid) {
    float hv[2];
    hv[0] = poll_f(&hin[tid]);
    hv[1] = poll_f(&hin[512 + tid]);
    const int gg = (tid >> 2) & 15, el = tid & 3;
#pragma unroll
    for (int e = 0; e < 2; ++e) {
        int c = (e << 3) + (tid >> 6);
        hs[c * 64 + (((gg + c) & 15) << 2) + el] = hv[e];
    }
}

__global__ __launch_bounds__(NTHR, 2) void k_fused(
    const float* __restrict__ x,
    const float* __restrict__ wih1, const float* __restrict__ bih1,
    const float* __restrict__ bhh1, const float* __restrict__ whh1,
    const float* __restrict__ wih2, const float* __restrict__ bih2,
    const float* __restrict__ bhh2, const float* __restrict__ whh2,
    const float* __restrict__ wfc, const float* __restrict__ bfc,
    const float* __restrict__ zbuf, float* __restrict__ htmpB, float* __restrict__ Hh,
    float* __restrict__ c1B, float* __restrict__ c2B,
    float* __restrict__ out)
{
    __shared__ __align__(16) float WihL[32 * WIH_LD];  // 66 KB
    __shared__ __align__(16) float WfcL[8 * 1024];     // 32 KB
    __shared__ __align__(16) float hs[HDIM];
    __shared__ __align__(16) float xbuf[IN_DIM];

    const int tid  = threadIdx.x;
    const int bid  = blockIdx.x;
    const bool is1 = (bid < NWGH);
    const int wg   = is1 ? bid : bid - NWGH;
    const int lane = tid & 63;
    const int wv   = tid >> 6;          // wave = h-output within WG's 8
    const int g    = lane >> 4;         // gate (i,f,g,o)
    const int lane16 = tid & 15;
    const int j    = wg * 8 + wv;       // owned h index
    const int R    = g * HDIM + j;      // whh/wih row for this 16-lane group

    const float* __restrict__ wih = is1 ? wih1 : wih2;
    const float* __restrict__ whh = is1 ? whh1 : whh2;
    const float* __restrict__ bih = is1 ? bih1 : bih2;
    const float* __restrict__ bhh = is1 ? bhh1 : bhh2;

    // stage this WG's 32 w_ih rows (local row r = wv*4+g <-> global g*H + wg*8 + wv)
    for (int idx = tid; idx < 32 * (IN_DIM / 4); idx += NTHR) {
        int r = idx >> 7, c4 = idx & 127;
        int grow = (r & 3) * HDIM + wg * 8 + (r >> 2);
        float4 v = ((const float4*)(wih + (size_t)grow * IN_DIM))[c4];
        *(float4*)&WihL[r * WIH_LD + c4 * 4] = v;
    }
    // cell1 WGs 0..124 own FC outputs o0..o0+7 (125*8 = 1000 exactly)
    const int o0 = wg * 8;
    const bool do_fc = is1 && (wg < 125);
    if (do_fc) {
        for (int idx = tid; idx < 8 * (HDIM / 4); idx += NTHR) {
            int r = idx >> 8, c4 = idx & 255;
            float4 v = ((const float4*)(wfc + (size_t)(o0 + r) * HDIM))[c4];
            *(float4*)&WfcL[r * 1024 + c4 * 4] = v;
        }
    }
    const float bgate = bih[R] + bhh[R];
    const float bfc_r = do_fc ? bfc[o0 + wv] : 0.f;

    // pin whh row slice: 64 floats/thread (elements [lane16*64, +64) of row R)
    float w[64];
    {
        const float4* p = (const float4*)(whh + (size_t)R * HDIM) + lane16 * 16;
#pragma unroll
        for (int m = 0; m < 16; ++m) {
            float4 v = p[m];
            w[4 * m + 0] = v.x; w[4 * m + 1] = v.y;
            w[4 * m + 2] = v.z; w[4 * m + 3] = v.w;
        }
#pragma unroll
        for (int m = 0; m < 64; ++m) asm volatile("" : "+v"(w[m]));
    }

#pragma unroll 1
    for (int t = 0; t < NSTEP; ++t) {
        // ---- pre-work (hidden under the other half's phase) ----
        if (tid < 128) {   // stage x[t] row 1023, scaled by 255
            float4 v = ((const float4*)(x + ((size_t)t * 1024 + 1023) * IN_DIM))[tid];
            v.x *= 255.f; v.y *= 255.f; v.z *= 255.f; v.w *= 255.f;
            *(float4*)&xbuf[tid * 4] = v;
        }
        __syncthreads();   // xbuf ready; also orders prev-iter hs reads before new writes
        float av = 0.f;    // per-lane partial of wih[R]·(255 x[t])
        {
            const float* __restrict__ wr = &WihL[(wv * 4 + g) * WIH_LD];
#pragma unroll
            for (int m = 0; m < 32; ++m)
                av += wr[lane16 + 16 * m] * xbuf[lane16 + 16 * m];
        }
        // ---- poll + stage h; poll c (lane0) ----
        const float* hin = is1 ? ((t == 0) ? zbuf : (Hh + (size_t)(t - 1) * HDIM))
                               : (htmpB + (size_t)t * HDIM);
        load_h_poll(hin, hs, tid);
        float cl = 0.f;
        if (lane == 0 && !(is1 && t == 0)) {
            const float* cp = is1 ? &c2B[(size_t)(t - 1) * HDIM + j]
                                  : &c1B[(size_t)t * HDIM + j];
            cl = poll_f(cp);
        }
        const float cprev = __shfl(cl, 0);
        __syncthreads();
        // ---- matvec: 64 FMAs from VGPR weights x swizzled LDS h ----
        float a0 = 0.f, a1 = 0.f, a2 = 0.f, a3 = 0.f;
        const int hbase = lane16 * 64;
#pragma unroll
        for (int m = 0; m < 16; ++m) {
            const float4 h4 = *(const float4*)&hs[hbase + (((m + lane16) & 15) << 2)];
            a0 += w[4 * m + 0] * h4.x;
            a1 += w[4 * m + 1] * h4.y;
            a2 += w[4 * m + 2] * h4.z;
            a3 += w[4 * m + 3] * h4.w;
        }
        float acc = (a0 + a1) + (a2 + a3) + av;
        acc += __shfl_xor(acc, 8); acc += __shfl_xor(acc, 4);
        acc += __shfl_xor(acc, 2); acc += __shfl_xor(acc, 1);
        acc += bgate;
        const float iv = __shfl(acc, 0),  fv = __shfl(acc, 16),
                    gv = __shfl(acc, 32), ov = __shfl(acc, 48);
        const float cn = sigf(fv) * cprev + sigf(iv) * tanhf(gv);
        const float hn = sigf(ov) * tanhf(cn);
        if (lane == 0) {   // data stores ARE the release (write-once + sentinel)
            if (is1) {
                __hip_atomic_store(&c1B[(size_t)t * HDIM + j], cn,
                                   __ATOMIC_RELAXED, __HIP_MEMORY_SCOPE_AGENT);
                __hip_atomic_store(&htmpB[(size_t)t * HDIM + j], hn,
                                   __ATOMIC_RELAXED, __HIP_MEMORY_SCOPE_AGENT);
            } else {
                __hip_atomic_store(&c2B[(size_t)t * HDIM + j], cn,
                                   __ATOMIC_RELAXED, __HIP_MEMORY_SCOPE_AGENT);
                __hip_atomic_store(&Hh[(size_t)t * HDIM + j], hn,
                                   __ATOMIC_RELAXED, __HIP_MEMORY_SCOPE_AGENT);
            }
        }
        // ---- FC slice for out[t-1] from hs (= Hh[t-1]); off critical path ----
        if (do_fc && t > 0) {
            const float* __restrict__ wr = &WfcL[wv * 1024];
            const int ggi = (lane >> 2) & 15, ei = lane & 3;
            float p = 0.f;
#pragma unroll
            for (int m = 0; m < 16; ++m)
                p += wr[lane + 64 * m] * hs[m * 64 + (((ggi + m) & 15) << 2) + ei];
            p += __shfl_xor(p, 32); p += __shfl_xor(p, 16); p += __shfl_xor(p, 8);
            p += __shfl_xor(p, 4);  p += __shfl_xor(p, 2);  p += __shfl_xor(p, 1);
            if (lane == 0) out[(size_t)(t - 1) * ODIM + o0 + wv] = p + bfc_r;
        }
    }
    // tail: out[127] from Hh[127]
    if (do_fc) {
        __syncthreads();   // everyone done reading hs from t=127
        load_h_poll(Hh + (size_t)(NSTEP - 1) * HDIM, hs, tid);
        __syncthreads();
        const float* __restrict__ wr = &WfcL[wv * 1024];
        const int ggi = (lane >> 2) & 15, ei = lane & 3;
        float p = 0.f;
#pragma unroll
        for (int m = 0; m < 16; ++m)
            p += wr[lane + 64 * m] * hs[m * 64 + (((ggi + m) & 15) << 2) + ei];
        p += __shfl_xor(p, 32); p += __shfl_xor(p, 16); p += __shfl_xor(p, 8);
        p += __shfl_xor(p, 4);  p += __shfl_xor(p, 2);  p += __shfl_xor(p, 1);
        if (lane == 0) out[(size_t)(NSTEP - 1) * ODIM + o0 + wv] = p + bfc_r;
    }
}

extern "C" void kernel_launch(void* const* d_in, const int* in_sizes, int n_in,
                              void* d_out, int out_size, void* d_ws, size_t ws_size,
                              hipStream_t stream) {
    const float* x    = (const float*)d_in[0];
    const float* wih1 = (const float*)d_in[1];
    const float* whh1 = (const float*)d_in[2];
    const float* bih1 = (const float*)d_in[3];
    const float* bhh1 = (const float*)d_in[4];
    const float* wih2 = (const float*)d_in[5];
    const float* whh2 = (const float*)d_in[6];
    const float* bih2 = (const float*)d_in[7];
    const float* bhh2 = (const float*)d_in[8];
    const float* wfc  = (const float*)d_in[9];
    const float* bfc  = (const float*)d_in[10];
    float* out = (float*)d_out;

    float* zbuf  = (float*)d_ws;                     // 1024
    float* htmpB = zbuf + HDIM;                      // 128*1024
    float* Hh    = htmpB + (size_t)NSTEP * HDIM;     // 128*1024
    float* c1B   = Hh + (size_t)NSTEP * HDIM;        // 128*1024
    float* c2B   = c1B + (size_t)NSTEP * HDIM;       // 128*1024

    hipLaunchKernelGGL(k_init, dim3(NWGH), dim3(NTHR), 0, stream,
                       zbuf, (unsigned int*)htmpB);
    hipLaunchKernelGGL(k_fused, dim3(2 * NWGH), dim3(NTHR), 0, stream,
                       x, wih1, bih1, bhh1, whh1, wih2, bih2, bhh2, whh2,
                       wfc, bfc, zbuf, htmpB, Hh, c1B, c2B, out);
}